// Round 1
// baseline (421.688 us; speedup 1.0000x reference)
//
#include <hip/hip_runtime.h>

#define NEG_INF  (-10000.0f)
#define L_SEQ    100
#define N_COLS   6464      // BS*(L+1)
#define D_       64
#define N_ROWS   6400      // BS*L
#define NVW      202       // N_COLS / 32

// workspace byte offsets
#define OFF_DEBIAS 0                     // float[6464]
#define OFF_VALIDW 25856                 // u32[202]
#define OFF_DUPW   26664                 // u32[64*202]
#define OFF_RLIST  78376                 // int[6400]
#define OFF_CNT    103976                // int[1]
#define OFF_ACCUM  103980                // float[1]

__global__ void zero_kernel(int* cnt, float* accum) {
  cnt[0] = 0;
  accum[0] = 0.0f;
}

// blocks 0..25 : debias per column + valid-row compaction
// block 26     : column-valid bitmask
// blocks 27..90: dup bitmask per sequence (64 sequences)
__global__ void prep_kernel(const float* __restrict__ pop,
                            const int* __restrict__ sid,
                            const int* __restrict__ log_mask,
                            float* __restrict__ debias,
                            unsigned* __restrict__ validw,
                            unsigned* __restrict__ dupw,
                            int* __restrict__ rlist,
                            int* __restrict__ cnt) {
  const int b = blockIdx.x, tid = threadIdx.x;
  if (b < 26) {
    int k = b * 256 + tid;
    if (k < N_COLS) debias[k] = __logf(pop[sid[k]]);
    if (k < N_ROWS && log_mask[k] != 0) {
      int slot = atomicAdd(cnt, 1);
      rlist[slot] = k;
    }
  } else if (b == 26) {
    if (tid < NVW) {
      unsigned bits = 0u;
      for (int bb = 0; bb < 32; ++bb) {
        int k = tid * 32 + bb;
        int i = k / 101, p = k - i * 101;
        int v = (p == 100) ? 1 : log_mask[i * L_SEQ + p];
        bits |= (unsigned)(v != 0) << bb;
      }
      validw[tid] = bits;
    }
  } else {
    int i = b - 27;
    __shared__ int ids[101];
    if (tid < 101) ids[tid] = sid[i * 101 + tid];
    __syncthreads();
    if (tid < NVW) {
      unsigned bits = 0u;
      for (int bb = 0; bb < 32; ++bb) {
        int k = tid * 32 + bb;
        int idk = sid[k];
        int hit = 0;
        for (int j = 0; j < 101; ++j) hit |= (ids[j] == idk) ? 1 : 0;
        bits |= (unsigned)(hit != 0) << bb;
      }
      dupw[i * NVW + tid] = bits;
    }
  }
}

// 8 compacted rows per block, 32 column-threads per row.
// Each thread: own row's prec vector in regs, streams score columns,
// online (max,sumexp) + target logit; 32-lane shfl reduce; 1 atomic/row.
__global__ __launch_bounds__(256) void main_kernel(
    const float* __restrict__ prec, const float* __restrict__ score,
    const float* __restrict__ debias, const unsigned* __restrict__ validw,
    const unsigned* __restrict__ dupw, const int* __restrict__ rlist,
    const int* __restrict__ cnt, float* __restrict__ accum) {
  const int nvalid = cnt[0];
  if (blockIdx.x * 8 >= nvalid) return;
  const int mr = threadIdx.x >> 5;
  const int mc = threadIdx.x & 31;
  const int ridx = blockIdx.x * 8 + mr;
  const bool act = (ridx < nvalid);
  const int r = act ? rlist[ridx] : 0;
  const int i = r / L_SEQ;
  const int j = r - i * L_SEQ;
  const int tgt = i * 101 + j + 1;

  float4 p[16];
  const float4* pp = (const float4*)(prec + (size_t)r * D_);
#pragma unroll
  for (int t = 0; t < 16; ++t) p[t] = pp[t];

  const unsigned* dupw_i = dupw + i * NVW;
  const unsigned kb = 1u << mc;  // k ≡ mc (mod 32)

  float mx = NEG_INF, sm = 0.0f, xt = NEG_INF;

  for (int k = mc; k < N_COLS; k += 32) {
    const float4* sp = (const float4*)(score + (size_t)k * D_);
    float acc = 0.0f;
#pragma unroll
    for (int t = 0; t < 16; ++t) {
      float4 s = sp[t];
      acc += p[t].x * s.x + p[t].y * s.y + p[t].z * s.z + p[t].w * s.w;
    }
    const int kw = k >> 5;
    float x = acc - debias[k];
    bool masked = ((validw[kw] & kb) == 0u) ||
                  (((dupw_i[kw] & kb) != 0u) && (k != tgt));
    x = masked ? NEG_INF : x;
    xt = (k == tgt) ? x : xt;
    float nm = fmaxf(mx, x);
    sm = sm * __expf(mx - nm) + __expf(x - nm);
    mx = nm;
  }

  // reduce (max,sumexp,xt) across the 32 column-lanes of this row
#pragma unroll
  for (int off = 16; off >= 1; off >>= 1) {
    float mo = __shfl_xor(mx, off);
    float so = __shfl_xor(sm, off);
    float to = __shfl_xor(xt, off);
    float nm = fmaxf(mx, mo);
    sm = sm * __expf(mx - nm) + so * __expf(mo - nm);
    mx = nm;
    xt = fmaxf(xt, to);
  }

  if (act && mc == 0) {
    float nll = (mx + __logf(sm)) - xt;
    atomicAdd(accum, nll);
  }
}

__global__ void fin_kernel(const float* accum, const int* cnt, float* out) {
  out[0] = accum[0] / (float)cnt[0];
}

extern "C" void kernel_launch(void* const* d_in, const int* in_sizes, int n_in,
                              void* d_out, int out_size, void* d_ws, size_t ws_size,
                              hipStream_t stream) {
  const float* prec  = (const float*)d_in[0];
  const float* score = (const float*)d_in[1];
  const float* pop   = (const float*)d_in[2];
  const int*   sid   = (const int*)d_in[3];
  const int*   lm    = (const int*)d_in[4];

  char* ws = (char*)d_ws;
  float*    debias = (float*)(ws + OFF_DEBIAS);
  unsigned* validw = (unsigned*)(ws + OFF_VALIDW);
  unsigned* dupw   = (unsigned*)(ws + OFF_DUPW);
  int*      rlist  = (int*)(ws + OFF_RLIST);
  int*      cnt    = (int*)(ws + OFF_CNT);
  float*    accum  = (float*)(ws + OFF_ACCUM);
  float*    out    = (float*)d_out;

  hipLaunchKernelGGL(zero_kernel, dim3(1), dim3(1), 0, stream, cnt, accum);
  hipLaunchKernelGGL(prep_kernel, dim3(91), dim3(256), 0, stream,
                     pop, sid, lm, debias, validw, dupw, rlist, cnt);
  hipLaunchKernelGGL(main_kernel, dim3(800), dim3(256), 0, stream,
                     prec, score, debias, validw, dupw, rlist, cnt, accum);
  hipLaunchKernelGGL(fin_kernel, dim3(1), dim3(1), 0, stream, accum, cnt, out);
}

// Round 2
// 81.961 us; speedup vs baseline: 5.1450x; 5.1450x over previous
//
#include <hip/hip_runtime.h>

#define NEG_INF  (-10000.0f)
#define L_SEQ    100
#define BS_      64
#define N_COLS   6464      // BS*(L+1)
#define D_       64
#define N_ROWS   6400      // BS*L
#define NWORDS   202       // N_COLS/32
#define NSPLIT   16

// ws byte offsets (16B-aligned)
#define OFF_SCBF   0          // ushort[6464*64]            827392
#define OFF_DEBIAS 827392     // float[6464]                 25856
#define OFF_CMB    853248     // u32[64*202]                 51712
#define OFF_XT     904960     // float[6400]                 25600
#define OFF_VFLAG  930560     // int[6400]                   25600
#define OFF_PM     956160     // float[16*6400]             409600
#define OFF_PS     1365760    // float[16*6400]             409600

typedef __attribute__((ext_vector_type(8))) short short8;
typedef __attribute__((ext_vector_type(4))) float f32x4;
union F8 { short8 v; unsigned short u[8]; };

__device__ __forceinline__ unsigned short f2bf(float f) {
  unsigned u = __float_as_uint(f);
  unsigned r = (u + 0x7FFFu + ((u >> 16) & 1u)) >> 16;
  return (unsigned short)r;
}

// blocks 0..201  : score f32->bf16 (8 elems/thread) + debias
// blocks 202..265: cmb[i][word] = valid & ~dup  (LDS item-bitset)
// blocks 266..290: exact f32 target logit xt[r] + vflag[r]
__global__ __launch_bounds__(256) void prep_kernel(
    const float* __restrict__ prec, const float* __restrict__ score,
    const float* __restrict__ pop, const int* __restrict__ sid,
    const int* __restrict__ lm,
    unsigned short* __restrict__ sc_bf, float* __restrict__ debias,
    unsigned* __restrict__ cmb, float* __restrict__ xt,
    int* __restrict__ vflag) {
  const int b = blockIdx.x, tid = threadIdx.x;
  __shared__ unsigned bset[3126];  // 100032 bits >= ITEM_NUM+1

  if (b < 202) {
    int g = b * 256 + tid;  // 51712 items of 8 floats
    const float4* sp = (const float4*)score + (size_t)g * 2;
    float4 a = sp[0], c = sp[1];
    F8 o;
    o.u[0] = f2bf(a.x); o.u[1] = f2bf(a.y); o.u[2] = f2bf(a.z); o.u[3] = f2bf(a.w);
    o.u[4] = f2bf(c.x); o.u[5] = f2bf(c.y); o.u[6] = f2bf(c.z); o.u[7] = f2bf(c.w);
    *((short8*)(sc_bf + (size_t)g * 8)) = o.v;
    if (g < N_COLS) debias[g] = __logf(pop[sid[g]]);
  } else if (b < 266) {
    const int i = b - 202;
    for (int w = tid; w < 3126; w += 256) bset[w] = 0u;
    __syncthreads();
    if (tid < 101) {
      int id = sid[i * 101 + tid];
      atomicOr(&bset[id >> 5], 1u << (id & 31));
    }
    __syncthreads();
    if (tid < NWORDS) {
      const int k0 = tid * 32;
      unsigned hitm = 0u, vm = 0u;
#pragma unroll
      for (int bb = 0; bb < 32; ++bb) {
        int k = k0 + bb;
        int id = sid[k];
        unsigned hit = (bset[id >> 5] >> (id & 31)) & 1u;
        hitm |= hit << bb;
        int i2 = k / 101, p = k - i2 * 101;
        int v = (p == 100) ? 1 : lm[i2 * L_SEQ + p];
        vm |= (unsigned)(v != 0) << bb;
      }
      cmb[i * NWORDS + tid] = vm & ~hitm;
    }
  } else {
    int r = (b - 266) * 256 + tid;  // 6400 rows
    int i = r / L_SEQ, j = r - i * L_SEQ;
    int tgt = i * 101 + j + 1;
    int p = j + 1;
    int vt = (p == 100) ? 1 : lm[i * L_SEQ + p];
    const float4* pr = (const float4*)(prec + (size_t)r * D_);
    const float4* sr = (const float4*)(score + (size_t)tgt * D_);
    float acc = 0.f;
#pragma unroll
    for (int t = 0; t < 16; ++t) {
      float4 pa = pr[t], sa = sr[t];
      acc += pa.x * sa.x + pa.y * sa.y + pa.z * sa.z + pa.w * sa.w;
    }
    float db = __logf(pop[sid[tgt]]);
    xt[r] = vt ? (acc - db) : NEG_INF;
    vflag[r] = vt;
  }
}

// grid (100, 16), 256 threads = 4 waves. Wave owns 16 rows x 1/16 of columns.
__global__ __launch_bounds__(256) void main_kernel(
    const float* __restrict__ prec, const unsigned short* __restrict__ sc_bf,
    const float* __restrict__ debias, const unsigned* __restrict__ cmb,
    float* __restrict__ pm, float* __restrict__ ps) {
  const int w = threadIdx.x >> 6;
  const int lane = threadIdx.x & 63;
  const int lr = lane & 15;      // frag row/col
  const int lk = lane >> 4;      // k-chunk
  const int rowbase = blockIdx.x * 64 + w * 16;
  const int split = blockIdx.y;

  // A fragments: prec rows (f32 -> bf16 on the fly), held for the whole kernel
  const float* prow = prec + (size_t)(rowbase + lr) * D_ + lk * 8;
  F8 fa0, fa1;
  {
    float4 a0 = *(const float4*)(prow);
    float4 a1 = *(const float4*)(prow + 4);
    float4 b0 = *(const float4*)(prow + 32);
    float4 b1 = *(const float4*)(prow + 36);
    fa0.u[0] = f2bf(a0.x); fa0.u[1] = f2bf(a0.y); fa0.u[2] = f2bf(a0.z); fa0.u[3] = f2bf(a0.w);
    fa0.u[4] = f2bf(a1.x); fa0.u[5] = f2bf(a1.y); fa0.u[6] = f2bf(a1.z); fa0.u[7] = f2bf(a1.w);
    fa1.u[0] = f2bf(b0.x); fa1.u[1] = f2bf(b0.y); fa1.u[2] = f2bf(b0.z); fa1.u[3] = f2bf(b0.w);
    fa1.u[4] = f2bf(b1.x); fa1.u[5] = f2bf(b1.y); fa1.u[6] = f2bf(b1.z); fa1.u[7] = f2bf(b1.w);
  }

  // this lane's 4 accumulator rows: rbase4 .. rbase4+3
  const int rbase4 = rowbase + lk * 4;
  const int i_a = rbase4 / L_SEQ;
  const int i_b = (rbase4 + 3) / L_SEQ;
  const int lim = (i_a + 1) * L_SEQ;
  const unsigned* cmb_a = cmb + i_a * NWORDS;
  const unsigned* cmb_b = cmb + i_b * NWORDS;

  float m[4] = {NEG_INF, NEG_INF, NEG_INF, NEG_INF};
  float s[4] = {0.f, 0.f, 0.f, 0.f};

  for (int st = split; st < 101; st += NSPLIT) {
    const int cbase = st * 64;
    // B fragments: 64 score columns (= score rows), bf16
    F8 fb0[4], fb1[4];
#pragma unroll
    for (int t = 0; t < 4; ++t) {
      const unsigned short* sp = sc_bf + (size_t)(cbase + t * 16 + lr) * D_ + lk * 8;
      fb0[t].v = *(const short8*)(sp);
      fb1[t].v = *(const short8*)(sp + 32);
    }
    f32x4 acc[4];
#pragma unroll
    for (int t = 0; t < 4; ++t) {
      f32x4 z = {0.f, 0.f, 0.f, 0.f};
      z = __builtin_amdgcn_mfma_f32_16x16x32_bf16(fa0.v, fb0[t].v, z, 0, 0, 0);
      z = __builtin_amdgcn_mfma_f32_16x16x32_bf16(fa1.v, fb1[t].v, z, 0, 0, 0);
      acc[t] = z;
    }
    float db0 = debias[cbase + lr];
    float db1 = debias[cbase + 16 + lr];
    float db2 = debias[cbase + 32 + lr];
    float db3 = debias[cbase + 48 + lr];
    const int kw = cbase >> 5;
    unsigned wa0 = cmb_a[kw], wa1 = cmb_a[kw + 1];
    unsigned wb0 = cmb_b[kw], wb1 = cmb_b[kw + 1];
    const int bp0 = lr, bp1 = 16 + lr;
#pragma unroll
    for (int q = 0; q < 4; ++q) {
      const bool ub = (rbase4 + q) >= lim;
      const unsigned w0 = ub ? wb0 : wa0;
      const unsigned w1 = ub ? wb1 : wa1;
      float x0 = ((w0 >> bp0) & 1u) ? (acc[0][q] - db0) : NEG_INF;
      float x1 = ((w0 >> bp1) & 1u) ? (acc[1][q] - db1) : NEG_INF;
      float x2 = ((w1 >> bp0) & 1u) ? (acc[2][q] - db2) : NEG_INF;
      float x3 = ((w1 >> bp1) & 1u) ? (acc[3][q] - db3) : NEG_INF;
      float nm = fmaxf(fmaxf(fmaxf(x0, x1), fmaxf(x2, x3)), m[q]);
      float sn = s[q] * __expf(m[q] - nm) + __expf(x0 - nm) + __expf(x1 - nm) +
                 __expf(x2 - nm) + __expf(x3 - nm);
      s[q] = (nm > -5.0e3f) ? sn : s[q];
      m[q] = nm;
    }
  }

  // reduce (m,s) across the 16 lanes (lr) sharing each row
#pragma unroll
  for (int q = 0; q < 4; ++q) {
#pragma unroll
    for (int off = 1; off < 16; off <<= 1) {
      float mo = __shfl_xor(m[q], off);
      float so = __shfl_xor(s[q], off);
      float nm = fmaxf(m[q], mo);
      s[q] = s[q] * __expf(m[q] - nm) + so * __expf(mo - nm);
      m[q] = nm;
    }
  }
  if (lr == 0) {
#pragma unroll
    for (int q = 0; q < 4; ++q) {
      pm[split * N_ROWS + rbase4 + q] = m[q];
      ps[split * N_ROWS + rbase4 + q] = s[q];
    }
  }
}

__global__ __launch_bounds__(1024) void merge_kernel(
    const float* __restrict__ pm, const float* __restrict__ ps,
    const float* __restrict__ xt, const int* __restrict__ vflag,
    const int* __restrict__ lm, float* __restrict__ out) {
  float sum = 0.f, cnt = 0.f;
  for (int r = threadIdx.x; r < N_ROWS; r += 1024) {
    if (!lm[r]) continue;
    float m = NEG_INF, s = 0.f;
#pragma unroll
    for (int p = 0; p < NSPLIT; ++p) {
      float mp = pm[p * N_ROWS + r], sp = ps[p * N_ROWS + r];
      float nm = fmaxf(m, mp);
      s = s * __expf(m - nm) + sp * __expf(mp - nm);
      m = nm;
    }
    float x = xt[r];
    if (vflag[r]) {
      float nm = fmaxf(m, x);
      s = s * __expf(m - nm) + __expf(x - nm);
      m = nm;
    }
    sum += (m + __logf(s)) - x;
    cnt += 1.f;
  }
  __shared__ float rs[1024], rc[1024];
  rs[threadIdx.x] = sum; rc[threadIdx.x] = cnt;
  __syncthreads();
  for (int o = 512; o > 0; o >>= 1) {
    if (threadIdx.x < o) {
      rs[threadIdx.x] += rs[threadIdx.x + o];
      rc[threadIdx.x] += rc[threadIdx.x + o];
    }
    __syncthreads();
  }
  if (threadIdx.x == 0) out[0] = rs[0] / rc[0];
}

extern "C" void kernel_launch(void* const* d_in, const int* in_sizes, int n_in,
                              void* d_out, int out_size, void* d_ws, size_t ws_size,
                              hipStream_t stream) {
  const float* prec  = (const float*)d_in[0];
  const float* score = (const float*)d_in[1];
  const float* pop   = (const float*)d_in[2];
  const int*   sid   = (const int*)d_in[3];
  const int*   lm    = (const int*)d_in[4];

  char* ws = (char*)d_ws;
  unsigned short* sc_bf  = (unsigned short*)(ws + OFF_SCBF);
  float*          debias = (float*)(ws + OFF_DEBIAS);
  unsigned*       cmb    = (unsigned*)(ws + OFF_CMB);
  float*          xt     = (float*)(ws + OFF_XT);
  int*            vflag  = (int*)(ws + OFF_VFLAG);
  float*          pm     = (float*)(ws + OFF_PM);
  float*          ps     = (float*)(ws + OFF_PS);
  float*          out    = (float*)d_out;

  hipLaunchKernelGGL(prep_kernel, dim3(291), dim3(256), 0, stream,
                     prec, score, pop, sid, lm, sc_bf, debias, cmb, xt, vflag);
  hipLaunchKernelGGL(main_kernel, dim3(100, 16), dim3(256), 0, stream,
                     prec, sc_bf, debias, cmb, pm, ps);
  hipLaunchKernelGGL(merge_kernel, dim3(1), dim3(1024), 0, stream,
                     pm, ps, xt, vflag, lm, out);
}

// Round 3
// 70.354 us; speedup vs baseline: 5.9938x; 1.1650x over previous
//
#include <hip/hip_runtime.h>

#define NEG_INF  (-10000.0f)
#define L_SEQ    100
#define N_COLS   6464      // BS*(L+1)
#define D_       64
#define N_ROWS   6400      // BS*L
#define NSPLIT   16

// ws byte offsets
#define OFF_SCBF 0          // ushort[6464*64] = 827392 B (dead after main)
#define OFF_NLL  0          // float[6400]   (aliases SCBF; written by merge1 after main)
#define OFF_MD   827392     // ushort bf16 [64*6464] = 827392 B
#define OFF_XT   1654784    // float[6400] = 25600 B
#define OFF_PS   1680384    // float[6400*16] = 409600 B
// total 2089984 B

typedef __attribute__((ext_vector_type(8))) short short8;
typedef __attribute__((ext_vector_type(4))) float f32x4;
union F8 { short8 v; unsigned short u[8]; };

__device__ __forceinline__ unsigned short f2bf(float f) {
  unsigned u = __float_as_uint(f);
  unsigned r = (u + 0x7FFFu + ((u >> 16) & 1u)) >> 16;
  return (unsigned short)r;
}
__device__ __forceinline__ float bf2f(unsigned short u) {
  return __uint_as_float((unsigned)u << 16);
}

// blocks 0..201  : score f32->bf16 (8 elems/thread)
// blocks 202..265: md[i][k] = (valid[k] && !dup[i][k]) ? 1/pop[sid[k]] : 0  (bf16)
// blocks 266..290: exact f32 target logit xt[r] (NEG_INF if target col invalid)
__global__ __launch_bounds__(256) void prep_kernel(
    const float* __restrict__ prec, const float* __restrict__ score,
    const float* __restrict__ pop, const int* __restrict__ sid,
    const int* __restrict__ lm,
    unsigned short* __restrict__ sc_bf, unsigned short* __restrict__ md,
    float* __restrict__ xt) {
  const int b = blockIdx.x, tid = threadIdx.x;
  __shared__ unsigned bset[3126];  // 100032 bits >= ITEM_NUM+1

  if (b < 202) {
    int g = b * 256 + tid;  // 51712 chunks of 8 floats
    const float4* sp = (const float4*)score + (size_t)g * 2;
    float4 a = sp[0], c = sp[1];
    F8 o;
    o.u[0] = f2bf(a.x); o.u[1] = f2bf(a.y); o.u[2] = f2bf(a.z); o.u[3] = f2bf(a.w);
    o.u[4] = f2bf(c.x); o.u[5] = f2bf(c.y); o.u[6] = f2bf(c.z); o.u[7] = f2bf(c.w);
    *((short8*)(sc_bf + (size_t)g * 8)) = o.v;
  } else if (b < 266) {
    const int i = b - 202;
    for (int w = tid; w < 3126; w += 256) bset[w] = 0u;
    __syncthreads();
    if (tid < 101) {
      int id = sid[i * 101 + tid];
      atomicOr(&bset[id >> 5], 1u << (id & 31));
    }
    __syncthreads();
    for (int k = tid; k < N_COLS; k += 256) {
      int id = sid[k];
      unsigned hit = (bset[id >> 5] >> (id & 31)) & 1u;
      int i2 = k / 101, p = k - i2 * 101;
      int v = (p == 100) ? 1 : lm[i2 * L_SEQ + p];
      float val = (v != 0 && hit == 0u) ? (1.0f / pop[id]) : 0.0f;
      md[(size_t)i * N_COLS + k] = f2bf(val);
    }
  } else {
    int r = (b - 266) * 256 + tid;  // 6400 rows
    int i = r / L_SEQ, j = r - i * L_SEQ;
    int tgt = i * 101 + j + 1;
    int p = j + 1;
    int vt = (p == 100) ? 1 : lm[i * L_SEQ + p];
    const float4* pr = (const float4*)(prec + (size_t)r * D_);
    const float4* sr = (const float4*)(score + (size_t)tgt * D_);
    float acc = 0.f;
#pragma unroll
    for (int t = 0; t < 16; ++t) {
      float4 pa = pr[t], sa = sr[t];
      acc += pa.x * sa.x + pa.y * sa.y + pa.z * sa.z + pa.w * sa.w;
    }
    xt[r] = vt ? (acc - __logf(pop[sid[tgt]])) : NEG_INF;
  }
}

// grid (100, 16), 256 threads = 4 waves. Wave owns 16 rows x 1/16 of columns.
// No max tracking: s[t][q] += expf(acc) * md  (md=0 masks; 16 independent chains).
__global__ __launch_bounds__(256) void main_kernel(
    const float* __restrict__ prec, const unsigned short* __restrict__ sc_bf,
    const unsigned short* __restrict__ md, float* __restrict__ ps) {
  const int w = threadIdx.x >> 6;
  const int lane = threadIdx.x & 63;
  const int lr = lane & 15;      // frag row/col
  const int lk = lane >> 4;      // k-chunk
  const int rowbase = blockIdx.x * 64 + w * 16;
  const int split = blockIdx.y;

  // A fragments: prec rows (f32 -> bf16), held in regs
  const float* prow = prec + (size_t)(rowbase + lr) * D_ + lk * 8;
  F8 fa0, fa1;
  {
    float4 a0 = *(const float4*)(prow);
    float4 a1 = *(const float4*)(prow + 4);
    float4 b0 = *(const float4*)(prow + 32);
    float4 b1 = *(const float4*)(prow + 36);
    fa0.u[0] = f2bf(a0.x); fa0.u[1] = f2bf(a0.y); fa0.u[2] = f2bf(a0.z); fa0.u[3] = f2bf(a0.w);
    fa0.u[4] = f2bf(a1.x); fa0.u[5] = f2bf(a1.y); fa0.u[6] = f2bf(a1.z); fa0.u[7] = f2bf(a1.w);
    fa1.u[0] = f2bf(b0.x); fa1.u[1] = f2bf(b0.y); fa1.u[2] = f2bf(b0.z); fa1.u[3] = f2bf(b0.w);
    fa1.u[4] = f2bf(b1.x); fa1.u[5] = f2bf(b1.y); fa1.u[6] = f2bf(b1.z); fa1.u[7] = f2bf(b1.w);
  }

  const int rbase4 = rowbase + lk * 4;           // this lane's 4 acc rows
  const int i_a = rbase4 / L_SEQ;
  const int i_b = (rbase4 + 3) / L_SEQ;
  const int lim = (i_a + 1) * L_SEQ;
  const unsigned short* md_a = md + (size_t)i_a * N_COLS;
  const unsigned short* md_b = md + (size_t)i_b * N_COLS;

  float s[4][4];
#pragma unroll
  for (int t = 0; t < 4; ++t)
#pragma unroll
    for (int q = 0; q < 4; ++q) s[t][q] = 0.f;

  for (int st = split; st < 101; st += NSPLIT) {
    const int cbase = st * 64;
    F8 fb0[4], fb1[4];
#pragma unroll
    for (int t = 0; t < 4; ++t) {
      const unsigned short* sp = sc_bf + (size_t)(cbase + t * 16 + lr) * D_ + lk * 8;
      fb0[t].v = *(const short8*)(sp);
      fb1[t].v = *(const short8*)(sp + 32);
    }
    float ma[4], mb[4];
#pragma unroll
    for (int t = 0; t < 4; ++t) {
      const int c = cbase + t * 16 + lr;
      ma[t] = bf2f(md_a[c]);
      mb[t] = bf2f(md_b[c]);
    }
    f32x4 acc[4];
#pragma unroll
    for (int t = 0; t < 4; ++t) {
      f32x4 z = {0.f, 0.f, 0.f, 0.f};
      z = __builtin_amdgcn_mfma_f32_16x16x32_bf16(fa0.v, fb0[t].v, z, 0, 0, 0);
      z = __builtin_amdgcn_mfma_f32_16x16x32_bf16(fa1.v, fb1[t].v, z, 0, 0, 0);
      acc[t] = z;
    }
#pragma unroll
    for (int q = 0; q < 4; ++q) {
      const bool ub = (rbase4 + q) >= lim;
#pragma unroll
      for (int t = 0; t < 4; ++t) {
        const float mm = ub ? mb[t] : ma[t];
        s[t][q] = fmaf(__expf(acc[t][q]), mm, s[t][q]);
      }
    }
  }

  float sq[4];
#pragma unroll
  for (int q = 0; q < 4; ++q)
    sq[q] = (s[0][q] + s[1][q]) + (s[2][q] + s[3][q]);
#pragma unroll
  for (int q = 0; q < 4; ++q) {
#pragma unroll
    for (int off = 1; off < 16; off <<= 1)
      sq[q] += __shfl_xor(sq[q], off);
  }
  if (lr == 0) {
#pragma unroll
    for (int q = 0; q < 4; ++q)
      ps[(size_t)(rbase4 + q) * NSPLIT + split] = sq[q];
  }
}

// grid 25 x 256: per-row combine + target injection
__global__ __launch_bounds__(256) void merge1_kernel(
    const float* __restrict__ ps, const float* __restrict__ xt,
    const int* __restrict__ lm, float* __restrict__ nll) {
  int r = blockIdx.x * 256 + threadIdx.x;
  const float4* pp = (const float4*)(ps + (size_t)r * NSPLIT);
  float4 a = pp[0], b = pp[1], c = pp[2], d = pp[3];
  float s = ((a.x + a.y) + (a.z + a.w)) + ((b.x + b.y) + (b.z + b.w)) +
            ((c.x + c.y) + (c.z + c.w)) + ((d.x + d.y) + (d.z + d.w));
  float x = xt[r];
  s += __expf(x);  // exp(NEG_INF) == 0 when target col invalid
  nll[r] = (lm[r] != 0) ? (__logf(s) - x) : 0.0f;
}

__global__ __launch_bounds__(1024) void merge2_kernel(
    const float* __restrict__ nll, const int* __restrict__ lm,
    float* __restrict__ out) {
  float sum = 0.f, cnt = 0.f;
  for (int r = threadIdx.x; r < N_ROWS; r += 1024) {
    sum += nll[r];
    cnt += (lm[r] != 0) ? 1.f : 0.f;
  }
  __shared__ float rs[1024], rc[1024];
  rs[threadIdx.x] = sum; rc[threadIdx.x] = cnt;
  __syncthreads();
  for (int o = 512; o > 0; o >>= 1) {
    if (threadIdx.x < o) {
      rs[threadIdx.x] += rs[threadIdx.x + o];
      rc[threadIdx.x] += rc[threadIdx.x + o];
    }
    __syncthreads();
  }
  if (threadIdx.x == 0) out[0] = rs[0] / rc[0];
}

extern "C" void kernel_launch(void* const* d_in, const int* in_sizes, int n_in,
                              void* d_out, int out_size, void* d_ws, size_t ws_size,
                              hipStream_t stream) {
  const float* prec  = (const float*)d_in[0];
  const float* score = (const float*)d_in[1];
  const float* pop   = (const float*)d_in[2];
  const int*   sid   = (const int*)d_in[3];
  const int*   lm    = (const int*)d_in[4];

  char* ws = (char*)d_ws;
  unsigned short* sc_bf = (unsigned short*)(ws + OFF_SCBF);
  unsigned short* md    = (unsigned short*)(ws + OFF_MD);
  float*          xt    = (float*)(ws + OFF_XT);
  float*          ps    = (float*)(ws + OFF_PS);
  float*          nll   = (float*)(ws + OFF_NLL);  // aliases sc_bf (dead after main)
  float*          out   = (float*)d_out;

  hipLaunchKernelGGL(prep_kernel, dim3(291), dim3(256), 0, stream,
                     prec, score, pop, sid, lm, sc_bf, md, xt);
  hipLaunchKernelGGL(main_kernel, dim3(100, 16), dim3(256), 0, stream,
                     prec, sc_bf, md, ps);
  hipLaunchKernelGGL(merge1_kernel, dim3(25), dim3(256), 0, stream,
                     ps, xt, lm, nll);
  hipLaunchKernelGGL(merge2_kernel, dim3(1), dim3(1024), 0, stream,
                     nll, lm, out);
}